// Round 1
// baseline (114.462 us; speedup 1.0000x reference)
//
#include <hip/hip_runtime.h>
#include <cmath>

// Tiny transformer block, D=6, S=128, B=8192, fp32.
// R11 = R10's verified flash core with the two dual-stream attn_pair calls
// MERGED into one 4-stream jt-loop:
//  - vf/kf loaded once per jt, shared by 4 accumulator streams (vf reads
//    13->8; the 16-VGPR kf hoist is gone -- kf is re-read per jt via
//    immediate ds offsets, stride 384B). Freed registers fund the 2 extra
//    O accumulators: peak stays under the 64-VGPR / 8-waves-per-SIMD cliff.
//  - LDS map [K 3KB][Q 3KB][vt 1.9KB]; obuf (5KB) aliases K+Q (both dead
//    after the loop). Barrier 2 moves to after the loop (still 3 barriers;
//    waves run the whole loop barrier-free -> less lockstep).
//  - vt zero-row dropped: O cols 7..15 are discarded (l15<7 write guard),
//    so the l15>=7 lanes clamp to the ones-row instead. LDS 8320->8048B.
//  - Per-stream math byte-identical to the verified core -> absmax 0.03125.

typedef float    v2f  __attribute__((ext_vector_type(2)));
typedef float    f4v  __attribute__((ext_vector_type(4)));
typedef short    s4v  __attribute__((ext_vector_type(4)));   // 4 bf16 = 2 VGPRs
typedef uint32_t u2   __attribute__((ext_vector_type(2)));

constexpr int D = 6;
constexpr int S = 128;
#define EPS 1e-5f
#define RSQRT_D 0.4082482904638631f   // 1/sqrt(6)
#define LOG2E   1.4426950408889634f

#define EXP2F(x) __builtin_amdgcn_exp2f(x)
#define RCPF(x)  __builtin_amdgcn_rcpf(x)
#define PKFMA(a, b, c) __builtin_elementwise_fma((a), (b), (c))

union UA { uint32_t u[2]; u2 h; s4v v; };

__device__ __forceinline__ uint32_t pkbf(float hi, float lo) {
    return __builtin_amdgcn_perm(__builtin_bit_cast(uint32_t, hi),
                                 __builtin_bit_cast(uint32_t, lo),
                                 0x07060302u);
}
__device__ __forceinline__ uint16_t bf16t(float x) {
    return (uint16_t)(__builtin_bit_cast(uint32_t, x) >> 16);
}

__device__ __forceinline__ f4v mfma16(s4v a, s4v b, f4v c) {
#if __has_builtin(__builtin_amdgcn_mfma_f32_16x16x16bf16_1k)
    return __builtin_amdgcn_mfma_f32_16x16x16bf16_1k(a, b, c, 0, 0, 0);
#else
    f4v d;
    asm volatile("v_mfma_f32_16x16x16_bf16 %0, %1, %2, %3\n\t"
                 "s_nop 7\n\ts_nop 2"
                 : "=v"(d) : "v"(a), "v"(b), "v"(c));
    return d;
#endif
}

// One QK->exp->PV step for one stream. diag folds at compile time (jt==Qi
// with unrolled jt). Arithmetic identical to the verified attn_pair body.
__device__ __forceinline__ f4v attn_step(bool diag, s4v kf, s4v qf, s4v vf,
                                         f4v O, int l15, int lq) {
    const f4v z = {0.f, 0.f, 0.f, 0.f};
    f4v c = mfma16(kf, qf, z);
    float p0 = EXP2F(c[0]);
    float p1 = EXP2F(c[1]);
    float p2 = EXP2F(c[2]);
    float p3 = EXP2F(c[3]);
    if (diag) {  // diagonal tile: causal mask, row k = lq*4+r, col q = l15
        p0 = (lq * 4 + 0 > l15) ? 0.f : p0;
        p1 = (lq * 4 + 1 > l15) ? 0.f : p1;
        p2 = (lq * 4 + 2 > l15) ? 0.f : p2;
        p3 = (lq * 4 + 3 > l15) ? 0.f : p3;
    }
    UA pa;
    pa.u[0] = pkbf(p1, p0);
    pa.u[1] = pkbf(p3, p2);
    return mfma16(pa.v, vf, O);
}

// Merged 4-stream causal pass: q-tiles Q0..Q3, one kf/vf load per jt shared
// by every active stream. K region stays live for the whole loop (obuf
// overwrite is deferred until after the post-loop barrier in the caller).
template<int Q0, int Q1, int Q2, int Q3>
__device__ __forceinline__ void attn_quad(
    const uint32_t (*Kr)[6], const uint16_t (*vt)[S + 8], int vne,
    UA q0, UA q1, UA q2, UA q3, f4v (&O)[4], int l15, int lq, int aoff)
{
    const f4v z = {0.f, 0.f, 0.f, 0.f};
    O[0] = z; O[1] = z; O[2] = z; O[3] = z;
    constexpr int M01  = Q0 > Q1 ? Q0 : Q1;
    constexpr int M23  = Q2 > Q3 ? Q2 : Q3;
    constexpr int JMAX = M01 > M23 ? M01 : M23;
    #pragma unroll
    for (int jt = 0; jt <= JMAX; ++jt) {
        UA kf; kf.h = *(const u2*)((const char*)&Kr[jt * 16 + l15][0] + aoff);
        UA vf; vf.h = *(const u2*)&vt[vne][jt * 16 + lq * 4];
        if (jt <= Q0) O[0] = attn_step(jt == Q0, kf.v, q0.v, vf.v, O[0], l15, lq);
        if (jt <= Q1) O[1] = attn_step(jt == Q1, kf.v, q1.v, vf.v, O[1], l15, lq);
        if (jt <= Q2) O[2] = attn_step(jt == Q2, kf.v, q2.v, vf.v, O[2], l15, lq);
        if (jt <= Q3) O[3] = attn_step(jt == Q3, kf.v, q3.v, vf.v, O[3], l15, lq);
    }
}

__global__ __launch_bounds__(S, 8) void txblock_kernel(
    const float* __restrict__ x,
    const float* __restrict__ ln1_w, const float* __restrict__ ln1_b,
    const float* __restrict__ wqkv,  const float* __restrict__ bqkv,
    const float* __restrict__ wo,    const float* __restrict__ bo,
    const float* __restrict__ ln2_w, const float* __restrict__ ln2_b,
    const float* __restrict__ w1,    const float* __restrict__ b1,
    const float* __restrict__ w2,    const float* __restrict__ b2,
    float* __restrict__ out)
{
    // LDS map (dwords):
    //   [   0,  768)  K rows: S x 6 dwords [f01,f23,f45,0,0,0], 24B stride
    //   [ 768, 1536)  Q rows: same layout
    //   [1536, 2012)  vt: 7 rows x (S+8) uint16 (d=0..5, row6 = ones)
    //   obuf = S x 10 floats = 1280 dwords, ALIASES K+Q (dead after loop);
    //   a barrier separates the last K read from the first obuf write.
    __shared__ __align__(16) uint32_t ldsbuf[2012];
    uint32_t (*Kr)[6]      = (uint32_t(*)[6])&ldsbuf[0];
    uint32_t (*Qr)[6]      = (uint32_t(*)[6])&ldsbuf[768];
    uint16_t (*vt)[S + 8]  = (uint16_t(*)[S + 8])&ldsbuf[1536];
    float    (*obuf)[10]   = (float(*)[10])&ldsbuf[0];

    const int b = blockIdx.x;
    const int s = threadIdx.x;
    const float* xrow = x + ((size_t)b * S + s) * D;
    float*      orow = out + ((size_t)b * S + s) * D;

    // ---- load x row ----
    v2f xv01 = ((const v2f*)xrow)[0];
    v2f xv23 = ((const v2f*)xrow)[1];
    v2f xv45 = ((const v2f*)xrow)[2];
    float xv[D] = {xv01[0], xv01[1], xv23[0], xv23[1], xv45[0], xv45[1]};

    // ---- ln1 ----
    float m = 0.f;
    #pragma unroll
    for (int d = 0; d < D; ++d) m += xv[d];
    m *= (1.0f / D);
    float var = 0.f;
    #pragma unroll
    for (int d = 0; d < D; ++d) { float t = xv[d] - m; var += t * t; }
    var *= (1.0f / D);
    float rstd = rsqrtf(var + EPS);
    float h1[D];
    #pragma unroll
    for (int d = 0; d < D; ++d)
        h1[d] = (xv[d] - m) * rstd * ln1_w[d] + ln1_b[d];

    // ---- qkv projection (packed; weights wave-uniform -> SGPRs) ----
    v2f aq[3], ak[3], av[3];
    #pragma unroll
    for (int jp = 0; jp < 3; ++jp) {
        aq[jp] = ((const v2f*)bqkv)[jp];
        ak[jp] = ((const v2f*)(bqkv + D))[jp];
        av[jp] = ((const v2f*)(bqkv + 2 * D))[jp];
    }
    #pragma unroll
    for (int d = 0; d < D; ++d) {
        const float* wrow = wqkv + d * 3 * D;
        v2f hd = {h1[d], h1[d]};
        #pragma unroll
        for (int jp = 0; jp < 3; ++jp) {
            aq[jp] = PKFMA(hd, ((const v2f*)wrow)[jp], aq[jp]);
            ak[jp] = PKFMA(hd, ((const v2f*)(wrow + D))[jp], ak[jp]);
            av[jp] = PKFMA(hd, ((const v2f*)(wrow + 2 * D))[jp], av[jp]);
        }
    }
    const v2f qscale = {RSQRT_D * LOG2E, RSQRT_D * LOG2E};

    // ---- stage Q, K, V^T ----
    #pragma unroll
    for (int jp = 0; jp < 3; ++jp) {
        v2f qs = aq[jp] * qscale;
        Qr[s][jp] = pkbf(qs[1], qs[0]);
        Kr[s][jp] = pkbf(ak[jp][1], ak[jp][0]);
    }
    Qr[s][3] = 0; Qr[s][4] = 0; Qr[s][5] = 0;
    Kr[s][3] = 0; Kr[s][4] = 0; Kr[s][5] = 0;
    vt[0][s] = bf16t(av[0][0]);
    vt[1][s] = bf16t(av[0][1]);
    vt[2][s] = bf16t(av[1][0]);
    vt[3][s] = bf16t(av[1][1]);
    vt[4][s] = bf16t(av[2][0]);
    vt[5][s] = bf16t(av[2][1]);
    vt[6][s] = 0x3F80;  // bf16 1.0 -> denominator column
    __syncthreads();     // barrier 1: staging visible

    // ---- hoist Q fragments only (Qr stays intact until barrier 2) ----
    const int wv  = s >> 6;
    const int l15 = s & 15;
    const int lq  = (s >> 4) & 3;
    const int aoff = (lq < 2) ? lq * 8 : 16;   // quads 2/3 -> zero pad
    const int vne  = (l15 < 7) ? l15 : 6;      // 0..5=V rows, >=6 -> ones row
                                               // (O cols 7..15 are discarded)
    const int qt0 = wv ? 1 : 0, qt1 = wv ? 6 : 7;
    const int qt2 = wv ? 2 : 3, qt3 = wv ? 5 : 4;
    UA q0, q1, q2, q3;
    q0.h = *(const u2*)((const char*)&Qr[qt0 * 16 + l15][0] + aoff);
    q1.h = *(const u2*)((const char*)&Qr[qt1 * 16 + l15][0] + aoff);
    q2.h = *(const u2*)((const char*)&Qr[qt2 * 16 + l15][0] + aoff);
    q3.h = *(const u2*)((const char*)&Qr[qt3 * 16 + l15][0] + aoff);

    // ---- flash attention: merged 4-stream core ----
    f4v O[4];
    if (wv == 0) attn_quad<0, 7, 3, 4>(Kr, vt, vne, q0, q1, q2, q3, O, l15, lq, aoff);
    else         attn_quad<1, 6, 2, 5>(Kr, vt, vne, q0, q1, q2, q3, O, l15, lq, aoff);
    __syncthreads();     // barrier 2: all K/Q/vt reads done before obuf overwrite

    // O: lane col=d=l15 (col 6 holds the denominator), rows q=lq*4+r
    if (l15 < 7) {
        #pragma unroll
        for (int r = 0; r < 4; ++r) {
            obuf[qt0 * 16 + lq * 4 + r][l15] = O[0][r];
            obuf[qt1 * 16 + lq * 4 + r][l15] = O[1][r];
            obuf[qt2 * 16 + lq * 4 + r][l15] = O[2][r];
            obuf[qt3 * 16 + lq * 4 + r][l15] = O[3][r];
        }
    }
    __syncthreads();     // barrier 3: obuf visible cross-wave

    // ---- epilogue: re-read x (L2-hot), per-thread packed ----
    v2f rx01 = ((const v2f*)xrow)[0];
    v2f rx23 = ((const v2f*)xrow)[1];
    v2f rx45 = ((const v2f*)xrow)[2];

    v2f o01 = *(const v2f*)&obuf[s][0];
    v2f o23 = *(const v2f*)&obuf[s][2];
    v2f o45 = *(const v2f*)&obuf[s][4];
    float invl = RCPF(obuf[s][6]);
    v2f il = {invl, invl};
    o01 *= il; o23 *= il; o45 *= il;
    float av6[D] = {o01[0], o01[1], o23[0], o23[1], o45[0], o45[1]};

    v2f xvp[3] = {rx01, rx23, rx45};
    v2f x2p[3];
    #pragma unroll
    for (int dp = 0; dp < 3; ++dp) {
        v2f o = ((const v2f*)bo)[dp];
        #pragma unroll
        for (int e = 0; e < D; ++e) {
            v2f we = ((const v2f*)(wo + e * D))[dp];
            v2f ae = {av6[e], av6[e]};
            o = PKFMA(ae, we, o);
        }
        x2p[dp] = o + xvp[dp];
    }
    float x2[D] = {x2p[0][0], x2p[0][1], x2p[1][0], x2p[1][1], x2p[2][0], x2p[2][1]};

    float m2 = 0.f;
    #pragma unroll
    for (int d = 0; d < D; ++d) m2 += x2[d];
    m2 *= (1.0f / D);
    float var2 = 0.f;
    #pragma unroll
    for (int d = 0; d < D; ++d) { float t = x2[d] - m2; var2 += t * t; }
    var2 *= (1.0f / D);
    float rstd2 = rsqrtf(var2 + EPS);
    float h2[D];
    #pragma unroll
    for (int d = 0; d < D; ++d)
        h2[d] = (x2[d] - m2) * rstd2 * ln2_w[d] + ln2_b[d];

    v2f ap[3];
    #pragma unroll
    for (int jp = 0; jp < 3; ++jp) {
        v2f a = ((const v2f*)b1)[jp];
        #pragma unroll
        for (int d = 0; d < D; ++d) {
            v2f wd = ((const v2f*)(w1 + d * D))[jp];
            v2f hd = {h2[d], h2[d]};
            a = PKFMA(hd, wd, a);
        }
        ap[jp] = a;
    }
    float g[D];
    #pragma unroll
    for (int j = 0; j < D; ++j) {
        float a = ap[j >> 1][j & 1];
        float t  = a * a;
        float in = fmaf(0.044715f * t, a, a);
        float e  = EXP2F(in * -2.3022229f);
        float r  = RCPF(1.0f + e);
        g[j] = a * r;
    }
    #pragma unroll
    for (int dp = 0; dp < 3; ++dp) {
        v2f a = ((const v2f*)b2)[dp];
        #pragma unroll
        for (int e = 0; e < D; ++e) {
            v2f we = ((const v2f*)(w2 + e * D))[dp];
            v2f ge = {g[e], g[e]};
            a = PKFMA(ge, we, a);
        }
        ((v2f*)orow)[dp] = x2p[dp] + a;
    }
}

extern "C" void kernel_launch(void* const* d_in, const int* in_sizes, int n_in,
                              void* d_out, int out_size, void* d_ws, size_t ws_size,
                              hipStream_t stream) {
    const float* x     = (const float*)d_in[0];
    const float* ln1_w = (const float*)d_in[1];
    const float* ln1_b = (const float*)d_in[2];
    const float* wqkv  = (const float*)d_in[3];
    const float* bqkv  = (const float*)d_in[4];
    const float* wo    = (const float*)d_in[5];
    const float* bo    = (const float*)d_in[6];
    const float* ln2_w = (const float*)d_in[7];
    const float* ln2_b = (const float*)d_in[8];
    const float* w1    = (const float*)d_in[9];
    const float* b1    = (const float*)d_in[10];
    const float* w2    = (const float*)d_in[11];
    const float* b2    = (const float*)d_in[12];
    float* out = (float*)d_out;

    const int B = in_sizes[0] / (S * D);
    txblock_kernel<<<B, S, 0, stream>>>(x, ln1_w, ln1_b, wqkv, bqkv, wo, bo,
                                        ln2_w, ln2_b, w1, b1, w2, b2, out);
}